// Round 5
// baseline (580.363 us; speedup 1.0000x reference)
//
#include <hip/hip_runtime.h>
#include <stdint.h>
#include <stddef.h>

#define Bsz 8
#define Ssz 1025
#define Esz 1408
#define Hsz 16
#define Dsz 88
#define Msz (Bsz * Ssz)      // 8200
#define HALF_E (Esz / 2)     // 704
#define HALF_D (Dsz / 2)     // 44
#define SPAD 1088            // 17*64, padded seq length for V^T
#define QSC 0.15379182f      // 88^-0.5 * log2(e): scores come out in log2 units

typedef __attribute__((ext_vector_type(8))) short short8;
typedef __attribute__((ext_vector_type(4))) float f32x4;

__device__ __forceinline__ unsigned short f2bf(float f) {
  union { float f; unsigned u; } v; v.f = f;
  unsigned r = v.u + 0x7fffu + ((v.u >> 16) & 1u);
  return (unsigned short)(r >> 16);
}
__device__ __forceinline__ unsigned fbits(float f) {
  union { float f; unsigned u; } v; v.f = f; return v.u;
}
__device__ __forceinline__ float fexp2(float x) {
#if __has_builtin(__builtin_amdgcn_exp2f)
  return __builtin_amdgcn_exp2f(x);
#else
  return __expf(x * 0.6931471805599453f);
#endif
}

// ---------------- fp32 -> bf16 cast (vectorized x4) ----------------
__global__ void cast_kernel(const float* __restrict__ in, unsigned short* __restrict__ out, int n4) {
  int i = blockIdx.x * blockDim.x + threadIdx.x;
  if (i >= n4) return;
  float4 v = ((const float4*)in)[i];
  uint2 o;
  o.x = (unsigned)f2bf(v.x) | ((unsigned)f2bf(v.y) << 16);
  o.y = (unsigned)f2bf(v.z) | ((unsigned)f2bf(v.w) << 16);
  ((uint2*)out)[i] = o;
}

// 4 equal-size fp32 weights -> one contiguous bf16 region (one launch)
__global__ void cast4_kernel(const float* __restrict__ a, const float* __restrict__ b,
                             const float* __restrict__ c, const float* __restrict__ d,
                             unsigned short* __restrict__ out, int n4each) {
  int i = blockIdx.x * blockDim.x + threadIdx.x;
  if (i >= 4 * n4each) return;
  int sel = i / n4each, off = i - sel * n4each;
  const float* src = (sel == 0) ? a : (sel == 1) ? b : (sel == 2) ? c : d;
  float4 v = ((const float4*)src)[off];
  uint2 o;
  o.x = (unsigned)f2bf(v.x) | ((unsigned)f2bf(v.y) << 16);
  o.y = (unsigned)f2bf(v.z) | ((unsigned)f2bf(v.w) << 16);
  ((uint2*)(out))[i] = o;
}

// ---------------- plain GEMM (final projection): C = A*Bw^T + bias ----------------
template <int OUT_BF16>
__global__ __launch_bounds__(256)
void gemm_bt(const unsigned short* __restrict__ A, const unsigned short* __restrict__ Bw,
             const float* __restrict__ bias, void* __restrict__ Cout,
             int M, int N, int K) {
  __shared__ __attribute__((aligned(16))) unsigned short sA[128 * 32];
  __shared__ __attribute__((aligned(16))) unsigned short sB[128 * 32];
  const int tid  = threadIdx.x;
  const int wave = tid >> 6;
  const int lane = tid & 63;
  const int m0 = blockIdx.y * 128;
  const int n0 = blockIdx.x * 128;
  const int wm = (wave >> 1) * 64;
  const int wn = (wave & 1) * 64;
  const int l15 = lane & 15;
  const int q8  = (lane >> 4) * 8;
  const int lr  = lane >> 2;
  const int lc  = (lane & 3) * 8;

  const f32x4 z4 = {0.f, 0.f, 0.f, 0.f};
  f32x4 acc[4][4];
  for (int i = 0; i < 4; i++)
    for (int j = 0; j < 4; j++) acc[i][j] = z4;

  for (int k0 = 0; k0 < K; k0 += 32) {
    __syncthreads();
#pragma unroll
    for (int c = 0; c < 2; c++) {
      int row = wave * 32 + c * 16;
      int gm = m0 + row + lr; if (gm > M - 1) gm = M - 1;
      const unsigned short* gpa = A + (size_t)gm * K + (k0 + lc);
      __builtin_amdgcn_global_load_lds(
          (__attribute__((address_space(1))) void*)gpa,
          (__attribute__((address_space(3))) void*)(&sA[row * 32]),
          16, 0, 0);
      int gn = n0 + row + lr;
      const unsigned short* gpb = Bw + (size_t)gn * K + (k0 + lc);
      __builtin_amdgcn_global_load_lds(
          (__attribute__((address_space(1))) void*)gpb,
          (__attribute__((address_space(3))) void*)(&sB[row * 32]),
          16, 0, 0);
    }
    __syncthreads();

    short8 af[4], bfv[4];
#pragma unroll
    for (int i = 0; i < 4; i++) af[i]  = *(const short8*)&sA[(wm + i * 16 + l15) * 32 + q8];
#pragma unroll
    for (int j = 0; j < 4; j++) bfv[j] = *(const short8*)&sB[(wn + j * 16 + l15) * 32 + q8];
#pragma unroll
    for (int i = 0; i < 4; i++)
#pragma unroll
      for (int j = 0; j < 4; j++)
        acc[i][j] = __builtin_amdgcn_mfma_f32_16x16x32_bf16(af[i], bfv[j], acc[i][j], 0, 0, 0);
  }

#pragma unroll
  for (int i = 0; i < 4; i++) {
#pragma unroll
    for (int j = 0; j < 4; j++) {
      int n = n0 + wn + j * 16 + l15;
      float bias_n = bias[n];
#pragma unroll
      for (int r = 0; r < 4; r++) {
        int m = m0 + wm + i * 16 + (lane >> 4) * 4 + r;
        if (m < M) {
          float val = acc[i][j][r] + bias_n;
          if (OUT_BF16) ((unsigned short*)Cout)[(size_t)m * N + n] = f2bf(val);
          else          ((float*)Cout)[(size_t)m * N + n] = val;
        }
      }
    }
  }
}

// ---------------- fused QKV GEMM + bias + RoPE + q-prescale ----------------
__global__ __launch_bounds__(256)
void gemm_qkv(const unsigned short* __restrict__ A, const unsigned short* __restrict__ W,
              const float* __restrict__ bq, const float* __restrict__ bk,
              const float* __restrict__ bv,
              const float* __restrict__ cosp, const float* __restrict__ sinp,
              unsigned short* __restrict__ qkv, int M, int K) {
  __shared__ __attribute__((aligned(16))) unsigned short sA[128 * 32];
  __shared__ __attribute__((aligned(16))) unsigned short sB[128 * 32];
  const int tid  = threadIdx.x;
  const int wave = tid >> 6;
  const int lane = tid & 63;
  const int m0 = blockIdx.y * 128;
  const int n0 = blockIdx.x * 128;
  const int wm = (wave >> 1) * 64;
  const int wn = (wave & 1) * 64;
  const int l15 = lane & 15;
  const int q8  = (lane >> 4) * 8;
  const int quad4 = (lane >> 4) * 4;
  const int lr  = lane >> 2;
  const int lc  = (lane & 3) * 8;

  const f32x4 z4 = {0.f, 0.f, 0.f, 0.f};
  f32x4 acc[4][4];
  for (int i = 0; i < 4; i++)
    for (int j = 0; j < 4; j++) acc[i][j] = z4;

  for (int k0 = 0; k0 < K; k0 += 32) {
    __syncthreads();
#pragma unroll
    for (int c = 0; c < 2; c++) {
      int row = wave * 32 + c * 16;
      int gm = m0 + row + lr; if (gm > M - 1) gm = M - 1;
      const unsigned short* gpa = A + (size_t)gm * K + (k0 + lc);
      __builtin_amdgcn_global_load_lds(
          (__attribute__((address_space(1))) void*)gpa,
          (__attribute__((address_space(3))) void*)(&sA[row * 32]),
          16, 0, 0);
      int gn = n0 + row + lr;
      const unsigned short* gpb = W + (size_t)gn * K + (k0 + lc);
      __builtin_amdgcn_global_load_lds(
          (__attribute__((address_space(1))) void*)gpb,
          (__attribute__((address_space(3))) void*)(&sB[row * 32]),
          16, 0, 0);
    }
    __syncthreads();

    short8 af[4], bfv[4];
#pragma unroll
    for (int i = 0; i < 4; i++) af[i]  = *(const short8*)&sA[(wm + i * 16 + l15) * 32 + q8];
#pragma unroll
    for (int j = 0; j < 4; j++) bfv[j] = *(const short8*)&sB[(wn + j * 16 + l15) * 32 + q8];
#pragma unroll
    for (int i = 0; i < 4; i++)
#pragma unroll
      for (int j = 0; j < 4; j++)
        acc[i][j] = __builtin_amdgcn_mfma_f32_16x16x32_bf16(af[i], bfv[j], acc[i][j], 0, 0, 0);
  }

  const int sel   = blockIdx.x / 11;            // 0=q, 1=k, 2=v (block-uniform)
  const int nloc0 = (blockIdx.x % 11) * 128;
  const float* bias = (sel == 0) ? bq : (sel == 1) ? bk : bv;
  unsigned short* outb = qkv + (size_t)sel * ((size_t)Msz * Esz);

#pragma unroll
  for (int i = 0; i < 4; i++) {
#pragma unroll
    for (int j = 0; j < 4; j++) {
      int nl = nloc0 + wn + j * 16 + l15;       // column within E
      float bias_n = bias[nl];
      int dd = nl % Dsz;                         // within-head dim
      int jrot = dd >> 1;
      bool isEven = (nl & 1) == 0;
#pragma unroll
      for (int r = 0; r < 4; r++) {
        int m = m0 + wm + i * 16 + quad4 + r;
        float val = acc[i][j][r] + bias_n;
        if (sel < 2) {                           // RoPE on q,k (block-uniform branch)
          float pv = __shfl_xor(val, 1, 64);     // partner col (adjacent l15)
          int sp = m - (m / Ssz) * Ssz;          // s position (always < 1025)
          float c  = cosp[sp * HALF_D + jrot];
          float sn = sinp[sp * HALF_D + jrot];
          val = isEven ? (val * c - pv * sn) : (pv * sn + val * c);
        }
        if (sel == 0) val *= QSC;                // pre-scale q: scale*log2(e)
        if (m < M) outb[(size_t)m * Esz + nl] = f2bf(val);
      }
    }
  }
}

// ---------------- V transpose: vb (B*S, E) -> VT (B,H,D,SPAD) ----------------
__global__ __launch_bounds__(256)
void vtrans_kernel(const unsigned short* __restrict__ vb, unsigned short* __restrict__ vt) {
  __shared__ unsigned short sT[64 * 89 + 8];
  const int tid = threadIdx.x;
  const int st = blockIdx.x, hh = blockIdx.y, bb = blockIdx.z;
  const short8 z8 = {0, 0, 0, 0, 0, 0, 0, 0};
  const unsigned short* src = vb + (size_t)(bb * Ssz) * Esz + hh * Dsz;
#pragma unroll
  for (int it = 0; it < 3; it++) {
    int g = it * 256 + tid;
    if (g < 704) {
      int r = g / 11, gc = g - r * 11;
      int s = st * 64 + r;
      short8 v = z8;
      if (s < Ssz) v = *(const short8*)(src + (size_t)s * Esz + gc * 8);
#pragma unroll
      for (int i = 0; i < 8; i++) sT[r * 89 + gc * 8 + i] = v[i];
    }
  }
  __syncthreads();
  unsigned short* dst = vt + (size_t)((bb * Hsz + hh) * Dsz) * SPAD + st * 64;
#pragma unroll
  for (int it = 0; it < 3; it++) {
    int g = it * 256 + tid;
    if (g < 704) {
      int d = g >> 3, sc = g & 7;
      short8 v;
#pragma unroll
      for (int i = 0; i < 8; i++) v[i] = sT[(sc * 8 + i) * 89 + d];
      *(short8*)(dst + (size_t)d * SPAD + sc * 8) = v;
    }
  }
}

// ---------------- flash attention: 128 q-rows/block, S^T softmax ----------------
// grid (9 q-tiles, H, B), 4 waves; each wave owns 2 stripes of 16 q rows.
// K/V^T staging amortized over 2x the MFMA work vs the 64-row version.
// sP (64x72) reused serially per stripe — same-wave LDS ordering, no barrier.
__global__ __launch_bounds__(256)
void attn_kernel(const unsigned short* __restrict__ qp, const unsigned short* __restrict__ kp,
                 const unsigned short* __restrict__ vt, unsigned short* __restrict__ op) {
  __shared__ __attribute__((aligned(16))) unsigned short sK[64 * 88 + 16];
  __shared__ __attribute__((aligned(16))) unsigned short sVT[96 * 72];
  __shared__ __attribute__((aligned(16))) unsigned short sP[64 * 72];
  const int tid  = threadIdx.x;
  const int wave = tid >> 6, lane = tid & 63;
  const int qt = blockIdx.x, hh = blockIdx.y, bb = blockIdx.z;
  const int l15 = lane & 15, quad = lane >> 4;
  const int quad4 = quad * 4;
  const short8 z8 = {0, 0, 0, 0, 0, 0, 0, 0};

  // Q fragments in registers: 2 stripes x 3 k-chunks (pre-scaled at projection)
  short8 qf[2][3];
#pragma unroll
  for (int st2 = 0; st2 < 2; st2++) {
    int s = qt * 128 + st2 * 64 + wave * 16 + l15; if (s > Ssz - 1) s = Ssz - 1;
    const unsigned short* qrow = qp + (size_t)(bb * Ssz + s) * Esz + hh * Dsz;
#pragma unroll
    for (int ks = 0; ks < 3; ks++) {
      short8 v = z8;
      if (!(ks == 2 && quad == 3)) v = *(const short8*)(qrow + ks * 32 + quad * 8);
      qf[st2][ks] = v;
    }
  }

  const unsigned short* kbase  = kp + (size_t)(bb * Ssz) * Esz + hh * Dsz;
  const unsigned short* vtbase = vt + (size_t)((bb * Hsz + hh) * Dsz) * SPAD;
  unsigned* sPu = (unsigned*)sP;

  float m_i[2] = {-1e30f, -1e30f}, l_i[2] = {0.f, 0.f};
  const f32x4 z4 = {0.f, 0.f, 0.f, 0.f};
  f32x4 o_acc[2][6];
#pragma unroll
  for (int st2 = 0; st2 < 2; st2++)
#pragma unroll
    for (int jd = 0; jd < 6; jd++) o_acc[st2][jd] = z4;

  for (int kt = 0; kt < 17; kt++) {
    __syncthreads();  // previous iter's sK/sVT reads done
    // K tile: 64 keys x 88 -> contiguous LDS via global_load_lds width=16
    for (int c = wave; c < 11; c += 4) {
      int g = c * 64 + lane;
      int r = g / 11, gc = g - r * 11;
      int t = kt * 64 + r; if (t > Ssz - 1) t = Ssz - 1;
      const unsigned short* srcp = kbase + (size_t)t * Esz + gc * 8;
      __builtin_amdgcn_global_load_lds(
          (__attribute__((address_space(1))) void*)srcp,
          (__attribute__((address_space(3))) void*)(&sK[c * 512]),
          16, 0, 0);
    }
    // V^T tile: 88 rows (d) x 64 (t), LDS stride 72
#pragma unroll
    for (int it = 0; it < 3; it++) {
      int g = it * 256 + tid;
      if (g < 704) {
        int d = g >> 3, sc2 = g & 7;
        short8 v = *(const short8*)(vtbase + (size_t)d * SPAD + kt * 64 + sc2 * 8);
        *(short8*)&sVT[d * 72 + sc2 * 8] = v;
      }
    }
    __syncthreads();

#pragma unroll
    for (int st2 = 0; st2 < 2; st2++) {
      // S^T stripe: col = qrow (l15), row = key (j*16 + quad*4 + r)
      f32x4 stv[4];
#pragma unroll
      for (int j = 0; j < 4; j++) stv[j] = z4;
#pragma unroll
      for (int ks = 0; ks < 3; ks++) {
#pragma unroll
        for (int j = 0; j < 4; j++) {
          short8 bk8 = *(const short8*)&sK[(j * 16 + l15) * 88 + ks * 32 + quad * 8];
          stv[j] = __builtin_amdgcn_mfma_f32_16x16x32_bf16(bk8, qf[st2][ks], stv[j], 0, 0, 0);
        }
      }

      if (kt == 16) {  // keys 1025..1087 invalid (only key 1024 valid)
#pragma unroll
        for (int j = 0; j < 4; j++)
#pragma unroll
          for (int r = 0; r < 4; r++)
            if (j != 0 || r != 0) stv[j][r] = -1e30f;
        if (quad != 0) stv[0][0] = -1e30f;
      }

      // row max: 15 in-lane + 2 shuffle rounds
      float rmax = stv[0][0];
#pragma unroll
      for (int j = 0; j < 4; j++)
#pragma unroll
        for (int r = 0; r < 4; r++) rmax = fmaxf(rmax, stv[j][r]);
      rmax = fmaxf(rmax, __shfl_xor(rmax, 16, 64));
      rmax = fmaxf(rmax, __shfl_xor(rmax, 32, 64));

      float mnew = fmaxf(m_i[st2], rmax);
      float alpha = fexp2(m_i[st2] - mnew);
      m_i[st2] = mnew;

      float rsum = 0.f;
#pragma unroll
      for (int j = 0; j < 4; j++) {
        float p0 = fexp2(stv[j][0] - mnew);
        float p1 = fexp2(stv[j][1] - mnew);
        float p2 = fexp2(stv[j][2] - mnew);
        float p3 = fexp2(stv[j][3] - mnew);
        rsum += (p0 + p1) + (p2 + p3);
        unsigned w0 = __builtin_amdgcn_perm(fbits(p1) + 0x8000u, fbits(p0) + 0x8000u, 0x07060302u);
        unsigned w1 = __builtin_amdgcn_perm(fbits(p3) + 0x8000u, fbits(p2) + 0x8000u, 0x07060302u);
        int base = (wave * 16 + l15) * 36 + j * 8 + quad * 2;  // u32 idx (stride 72 ush)
        sPu[base]     = w0;
        sPu[base + 1] = w1;
      }
      rsum += __shfl_xor(rsum, 16, 64);
      rsum += __shfl_xor(rsum, 32, 64);
      l_i[st2] = l_i[st2] * alpha + rsum;

      float ar[4];
#pragma unroll
      for (int r = 0; r < 4; r++) ar[r] = __shfl(alpha, quad4 + r, 64);
#pragma unroll
      for (int jd = 0; jd < 6; jd++)
#pragma unroll
        for (int r = 0; r < 4; r++) o_acc[st2][jd][r] *= ar[r];

      // PV: same-wave sP round-trip (in-order LDS per wave), no barrier
#pragma unroll
      for (int ks2 = 0; ks2 < 2; ks2++) {
        short8 ap = *(const short8*)&sP[(wave * 16 + l15) * 72 + ks2 * 32 + quad * 8];
#pragma unroll
        for (int jd = 0; jd < 6; jd++) {
          short8 bv8 = *(const short8*)&sVT[(jd * 16 + l15) * 72 + ks2 * 32 + quad * 8];
          o_acc[st2][jd] = __builtin_amdgcn_mfma_f32_16x16x32_bf16(ap, bv8, o_acc[st2][jd], 0, 0, 0);
        }
      }
    }
  }

  // epilogue: normalize and store both stripes
#pragma unroll
  for (int st2 = 0; st2 < 2; st2++) {
    float lr4[4];
#pragma unroll
    for (int r = 0; r < 4; r++) lr4[r] = __shfl(l_i[st2], quad4 + r, 64);
#pragma unroll
    for (int jd = 0; jd < 6; jd++) {
      int d = jd * 16 + l15;
#pragma unroll
      for (int r = 0; r < 4; r++) {
        int s = qt * 128 + st2 * 64 + wave * 16 + quad4 + r;
        if (s < Ssz && d < Dsz) {
          float val = o_acc[st2][jd][r] / lr4[r];
          op[((size_t)(bb * Ssz + s)) * Esz + hh * Dsz + d] = f2bf(val);
        }
      }
    }
  }
}

// ---------------- launch ----------------
extern "C" void kernel_launch(void* const* d_in, const int* in_sizes, int n_in,
                              void* d_out, int out_size, void* d_ws, size_t ws_size,
                              hipStream_t stream) {
  const float* hs = (const float*)d_in[0];
  const float* fc = (const float*)d_in[1];
  const float* fs = (const float*)d_in[2];
  const float* Wq = (const float*)d_in[3];
  const float* bq = (const float*)d_in[4];
  const float* Wk = (const float*)d_in[5];
  const float* bk = (const float*)d_in[6];
  const float* Wv = (const float*)d_in[7];
  const float* bv = (const float*)d_in[8];
  const float* Wo = (const float*)d_in[9];
  const float* bo = (const float*)d_in[10];
  float* out = (float*)d_out;

  const size_t ME = (size_t)Msz * Esz;   // 11,545,600
  const size_t EE = (size_t)Esz * Esz;   // 1,982,464
  // Layout: hsb | wqb wkb wvb wob (4EE contiguous -> single cast4) | qb kb vb.
  // VT (12,255,232 ush) overlays hsb..wvb (ME+3EE = 17,492,992) — wob at
  // ME+3EE is beyond VT's end, stays live for the final GEMM.
  unsigned short* hsb = (unsigned short*)d_ws;
  unsigned short* wqb = hsb + ME;
  unsigned short* wkb = wqb + EE;
  unsigned short* wvb = wkb + EE;
  unsigned short* wob = wvb + EE;
  unsigned short* qb  = wob + EE;
  unsigned short* kb  = qb  + ME;
  unsigned short* vb  = kb  + ME;
  unsigned short* vtb = hsb;   // VT overlay
  unsigned short* aob = vb;    // attention output overlays vb (dead after vtrans)

  int nh4 = (int)(ME / 4);
  int nw4 = (int)(EE / 4);
  cast_kernel<<<(nh4 + 255) / 256, 256, 0, stream>>>(hs, hsb, nh4);
  cast4_kernel<<<(4 * nw4 + 255) / 256, 256, 0, stream>>>(Wq, Wk, Wv, Wo, wqb, nw4);

  // fused QKV projection + bias + RoPE + q prescale: N = 3*1408 = 4224
  dim3 gq(33, (Msz + 127) / 128);  // (33, 65)
  gemm_qkv<<<gq, 256, 0, stream>>>(hsb, wqb, bq, bk, bv, fc, fs, qb, Msz, Esz);

  vtrans_kernel<<<dim3(17, Hsz, Bsz), 256, 0, stream>>>(vb, vtb);

  attn_kernel<<<dim3(9, Hsz, Bsz), 256, 0, stream>>>(qb, kb, vtb, aob);

  dim3 gg(Esz / 128, (Msz + 127) / 128);  // (11, 65)
  gemm_bt<0><<<gg, 256, 0, stream>>>(aob, wob, bo, out, Msz, Esz, Esz);
}

// Round 6
// 511.676 us; speedup vs baseline: 1.1342x; 1.1342x over previous
//
#include <hip/hip_runtime.h>
#include <stdint.h>
#include <stddef.h>

#define Bsz 8
#define Ssz 1025
#define Esz 1408
#define Hsz 16
#define Dsz 88
#define Msz (Bsz * Ssz)      // 8200
#define HALF_E (Esz / 2)     // 704
#define HALF_D (Dsz / 2)     // 44
#define SPAD 1088            // 17*64, padded seq length for V^T
#define QSC 0.15379182f      // 88^-0.5 * log2(e): scores come out in log2 units

typedef __attribute__((ext_vector_type(8))) short short8;
typedef __attribute__((ext_vector_type(4))) float f32x4;

__device__ __forceinline__ unsigned short f2bf(float f) {
  union { float f; unsigned u; } v; v.f = f;
  unsigned r = v.u + 0x7fffu + ((v.u >> 16) & 1u);
  return (unsigned short)(r >> 16);
}
__device__ __forceinline__ unsigned fbits(float f) {
  union { float f; unsigned u; } v; v.f = f; return v.u;
}
__device__ __forceinline__ float fexp2(float x) {
#if __has_builtin(__builtin_amdgcn_exp2f)
  return __builtin_amdgcn_exp2f(x);
#else
  return __expf(x * 0.6931471805599453f);
#endif
}

// ---------------- fp32 -> bf16 cast (vectorized x4) ----------------
__global__ void cast_kernel(const float* __restrict__ in, unsigned short* __restrict__ out, int n4) {
  int i = blockIdx.x * blockDim.x + threadIdx.x;
  if (i >= n4) return;
  float4 v = ((const float4*)in)[i];
  uint2 o;
  o.x = (unsigned)f2bf(v.x) | ((unsigned)f2bf(v.y) << 16);
  o.y = (unsigned)f2bf(v.z) | ((unsigned)f2bf(v.w) << 16);
  ((uint2*)out)[i] = o;
}

// 4 equal-size fp32 weights -> one contiguous bf16 region (one launch)
__global__ void cast4_kernel(const float* __restrict__ a, const float* __restrict__ b,
                             const float* __restrict__ c, const float* __restrict__ d,
                             unsigned short* __restrict__ out, int n4each) {
  int i = blockIdx.x * blockDim.x + threadIdx.x;
  if (i >= 4 * n4each) return;
  int sel = i / n4each, off = i - sel * n4each;
  const float* src = (sel == 0) ? a : (sel == 1) ? b : (sel == 2) ? c : d;
  float4 v = ((const float4*)src)[off];
  uint2 o;
  o.x = (unsigned)f2bf(v.x) | ((unsigned)f2bf(v.y) << 16);
  o.y = (unsigned)f2bf(v.z) | ((unsigned)f2bf(v.w) << 16);
  ((uint2*)(out))[i] = o;
}

// ---------------- plain GEMM (final projection): C = A*Bw^T + bias ----------------
template <int OUT_BF16>
__global__ __launch_bounds__(256)
void gemm_bt(const unsigned short* __restrict__ A, const unsigned short* __restrict__ Bw,
             const float* __restrict__ bias, void* __restrict__ Cout,
             int M, int N, int K) {
  __shared__ __attribute__((aligned(16))) unsigned short sA[128 * 32];
  __shared__ __attribute__((aligned(16))) unsigned short sB[128 * 32];
  const int tid  = threadIdx.x;
  const int wave = tid >> 6;
  const int lane = tid & 63;
  const int m0 = blockIdx.y * 128;
  const int n0 = blockIdx.x * 128;
  const int wm = (wave >> 1) * 64;
  const int wn = (wave & 1) * 64;
  const int l15 = lane & 15;
  const int q8  = (lane >> 4) * 8;
  const int lr  = lane >> 2;
  const int lc  = (lane & 3) * 8;

  const f32x4 z4 = {0.f, 0.f, 0.f, 0.f};
  f32x4 acc[4][4];
  for (int i = 0; i < 4; i++)
    for (int j = 0; j < 4; j++) acc[i][j] = z4;

  for (int k0 = 0; k0 < K; k0 += 32) {
    __syncthreads();
#pragma unroll
    for (int c = 0; c < 2; c++) {
      int row = wave * 32 + c * 16;
      int gm = m0 + row + lr; if (gm > M - 1) gm = M - 1;
      const unsigned short* gpa = A + (size_t)gm * K + (k0 + lc);
      __builtin_amdgcn_global_load_lds(
          (__attribute__((address_space(1))) void*)gpa,
          (__attribute__((address_space(3))) void*)(&sA[row * 32]),
          16, 0, 0);
      int gn = n0 + row + lr;
      const unsigned short* gpb = Bw + (size_t)gn * K + (k0 + lc);
      __builtin_amdgcn_global_load_lds(
          (__attribute__((address_space(1))) void*)gpb,
          (__attribute__((address_space(3))) void*)(&sB[row * 32]),
          16, 0, 0);
    }
    __syncthreads();

    short8 af[4], bfv[4];
#pragma unroll
    for (int i = 0; i < 4; i++) af[i]  = *(const short8*)&sA[(wm + i * 16 + l15) * 32 + q8];
#pragma unroll
    for (int j = 0; j < 4; j++) bfv[j] = *(const short8*)&sB[(wn + j * 16 + l15) * 32 + q8];
#pragma unroll
    for (int i = 0; i < 4; i++)
#pragma unroll
      for (int j = 0; j < 4; j++)
        acc[i][j] = __builtin_amdgcn_mfma_f32_16x16x32_bf16(af[i], bfv[j], acc[i][j], 0, 0, 0);
  }

#pragma unroll
  for (int i = 0; i < 4; i++) {
#pragma unroll
    for (int j = 0; j < 4; j++) {
      int n = n0 + wn + j * 16 + l15;
      float bias_n = bias[n];
#pragma unroll
      for (int r = 0; r < 4; r++) {
        int m = m0 + wm + i * 16 + (lane >> 4) * 4 + r;
        if (m < M) {
          float val = acc[i][j][r] + bias_n;
          if (OUT_BF16) ((unsigned short*)Cout)[(size_t)m * N + n] = f2bf(val);
          else          ((float*)Cout)[(size_t)m * N + n] = val;
        }
      }
    }
  }
}

// ---------------- fused QKV GEMM + bias + RoPE + q-prescale ----------------
__global__ __launch_bounds__(256)
void gemm_qkv(const unsigned short* __restrict__ A, const unsigned short* __restrict__ W,
              const float* __restrict__ bq, const float* __restrict__ bk,
              const float* __restrict__ bv,
              const float* __restrict__ cosp, const float* __restrict__ sinp,
              unsigned short* __restrict__ qkv, int M, int K) {
  __shared__ __attribute__((aligned(16))) unsigned short sA[128 * 32];
  __shared__ __attribute__((aligned(16))) unsigned short sB[128 * 32];
  const int tid  = threadIdx.x;
  const int wave = tid >> 6;
  const int lane = tid & 63;
  const int m0 = blockIdx.y * 128;
  const int n0 = blockIdx.x * 128;
  const int wm = (wave >> 1) * 64;
  const int wn = (wave & 1) * 64;
  const int l15 = lane & 15;
  const int q8  = (lane >> 4) * 8;
  const int quad4 = (lane >> 4) * 4;
  const int lr  = lane >> 2;
  const int lc  = (lane & 3) * 8;

  const f32x4 z4 = {0.f, 0.f, 0.f, 0.f};
  f32x4 acc[4][4];
  for (int i = 0; i < 4; i++)
    for (int j = 0; j < 4; j++) acc[i][j] = z4;

  for (int k0 = 0; k0 < K; k0 += 32) {
    __syncthreads();
#pragma unroll
    for (int c = 0; c < 2; c++) {
      int row = wave * 32 + c * 16;
      int gm = m0 + row + lr; if (gm > M - 1) gm = M - 1;
      const unsigned short* gpa = A + (size_t)gm * K + (k0 + lc);
      __builtin_amdgcn_global_load_lds(
          (__attribute__((address_space(1))) void*)gpa,
          (__attribute__((address_space(3))) void*)(&sA[row * 32]),
          16, 0, 0);
      int gn = n0 + row + lr;
      const unsigned short* gpb = W + (size_t)gn * K + (k0 + lc);
      __builtin_amdgcn_global_load_lds(
          (__attribute__((address_space(1))) void*)gpb,
          (__attribute__((address_space(3))) void*)(&sB[row * 32]),
          16, 0, 0);
    }
    __syncthreads();

    short8 af[4], bfv[4];
#pragma unroll
    for (int i = 0; i < 4; i++) af[i]  = *(const short8*)&sA[(wm + i * 16 + l15) * 32 + q8];
#pragma unroll
    for (int j = 0; j < 4; j++) bfv[j] = *(const short8*)&sB[(wn + j * 16 + l15) * 32 + q8];
#pragma unroll
    for (int i = 0; i < 4; i++)
#pragma unroll
      for (int j = 0; j < 4; j++)
        acc[i][j] = __builtin_amdgcn_mfma_f32_16x16x32_bf16(af[i], bfv[j], acc[i][j], 0, 0, 0);
  }

  const int sel   = blockIdx.x / 11;            // 0=q, 1=k, 2=v (block-uniform)
  const int nloc0 = (blockIdx.x % 11) * 128;
  const float* bias = (sel == 0) ? bq : (sel == 1) ? bk : bv;
  unsigned short* outb = qkv + (size_t)sel * ((size_t)Msz * Esz);

#pragma unroll
  for (int i = 0; i < 4; i++) {
#pragma unroll
    for (int j = 0; j < 4; j++) {
      int nl = nloc0 + wn + j * 16 + l15;       // column within E
      float bias_n = bias[nl];
      int dd = nl % Dsz;                         // within-head dim
      int jrot = dd >> 1;
      bool isEven = (nl & 1) == 0;
#pragma unroll
      for (int r = 0; r < 4; r++) {
        int m = m0 + wm + i * 16 + quad4 + r;
        float val = acc[i][j][r] + bias_n;
        if (sel < 2) {                           // RoPE on q,k (block-uniform branch)
          float pv = __shfl_xor(val, 1, 64);     // partner col (adjacent l15)
          int sp = m - (m / Ssz) * Ssz;          // s position (always < 1025)
          float c  = cosp[sp * HALF_D + jrot];
          float sn = sinp[sp * HALF_D + jrot];
          val = isEven ? (val * c - pv * sn) : (pv * sn + val * c);
        }
        if (sel == 0) val *= QSC;                // pre-scale q: scale*log2(e)
        if (m < M) outb[(size_t)m * Esz + nl] = f2bf(val);
      }
    }
  }
}

// ---------------- V transpose: vb (B*S, E) -> VT (B,H,D,SPAD) ----------------
__global__ __launch_bounds__(256)
void vtrans_kernel(const unsigned short* __restrict__ vb, unsigned short* __restrict__ vt) {
  __shared__ unsigned short sT[64 * 89 + 8];
  const int tid = threadIdx.x;
  const int st = blockIdx.x, hh = blockIdx.y, bb = blockIdx.z;
  const short8 z8 = {0, 0, 0, 0, 0, 0, 0, 0};
  const unsigned short* src = vb + (size_t)(bb * Ssz) * Esz + hh * Dsz;
#pragma unroll
  for (int it = 0; it < 3; it++) {
    int g = it * 256 + tid;
    if (g < 704) {
      int r = g / 11, gc = g - r * 11;
      int s = st * 64 + r;
      short8 v = z8;
      if (s < Ssz) v = *(const short8*)(src + (size_t)s * Esz + gc * 8);
#pragma unroll
      for (int i = 0; i < 8; i++) sT[r * 89 + gc * 8 + i] = v[i];
    }
  }
  __syncthreads();
  unsigned short* dst = vt + (size_t)((bb * Hsz + hh) * Dsz) * SPAD + st * 64;
#pragma unroll
  for (int it = 0; it < 3; it++) {
    int g = it * 256 + tid;
    if (g < 704) {
      int d = g >> 3, sc = g & 7;
      short8 v;
#pragma unroll
      for (int i = 0; i < 8; i++) v[i] = sT[(sc * 8 + i) * 89 + d];
      *(short8*)(dst + (size_t)d * SPAD + sc * 8) = v;
    }
  }
}

// ---------------- flash attention: 64 q-rows/block, pipelined staging ----------------
// grid (17 q-tiles, H, B), 4 waves; wave owns 16 q rows (Q frags in regs,
// pre-scaled by 88^-0.5*log2e). Staging pipeline: K(kt+1) via global_load_lds
// into the ALTERNATE sK buffer + VT(kt+1) into regs, both issued at the start
// of compute(kt) — their vmcnt drain lands at the NEXT post-compute barrier,
// so the whole compute phase hides the HBM latency. sVT written from regs in
// the short section between the two barriers.
__global__ __launch_bounds__(256)
void attn_kernel(const unsigned short* __restrict__ qp, const unsigned short* __restrict__ kp,
                 const unsigned short* __restrict__ vt, unsigned short* __restrict__ op) {
  __shared__ __attribute__((aligned(16))) unsigned short sK[2][64 * 88];
  __shared__ __attribute__((aligned(16))) unsigned short sVT[96 * 72];
  __shared__ __attribute__((aligned(16))) unsigned short sP[64 * 72];
  const int tid  = threadIdx.x;
  const int wave = tid >> 6, lane = tid & 63;
  const int qt = blockIdx.x, hh = blockIdx.y, bb = blockIdx.z;
  const int l15 = lane & 15, quad = lane >> 4;
  const int quad4 = quad * 4;
  const short8 z8 = {0, 0, 0, 0, 0, 0, 0, 0};

  // Q fragments in registers (pre-scaled at projection)
  short8 qf[3];
  {
    int s = qt * 64 + wave * 16 + l15; if (s > Ssz - 1) s = Ssz - 1;
    const unsigned short* qrow = qp + (size_t)(bb * Ssz + s) * Esz + hh * Dsz;
#pragma unroll
    for (int ks = 0; ks < 3; ks++) {
      short8 v = z8;
      if (!(ks == 2 && quad == 3)) v = *(const short8*)(qrow + ks * 32 + quad * 8);
      qf[ks] = v;
    }
  }

  const unsigned short* kbase  = kp + (size_t)(bb * Ssz) * Esz + hh * Dsz;
  const unsigned short* vtbase = vt + (size_t)((bb * Hsz + hh) * Dsz) * SPAD;
  unsigned* sPu = (unsigned*)sP;

  // K-staging helper indices: chunk c covers granules c*64+lane
  const int kc_r[3]  = {(0 * 64 + lane) / 11, (4 * 64 + lane) / 11, (8 * 64 + lane) / 11};

  // ---- prologue: issue K(0) -> sK[0], load VT(0) -> regs ----
#pragma unroll
  for (int ci = 0; ci < 3; ci++) {
    int c = wave + ci * 4;
    if (c < 11) {
      int g = c * 64 + lane;
      int r = g / 11, gc = g - r * 11;
      int t = r;  // kt=0
      const unsigned short* srcp = kbase + (size_t)t * Esz + gc * 8;
      __builtin_amdgcn_global_load_lds(
          (__attribute__((address_space(1))) void*)srcp,
          (__attribute__((address_space(3))) void*)(&sK[0][c * 512]),
          16, 0, 0);
    }
  }
  short8 vreg[3];
#pragma unroll
  for (int it = 0; it < 3; it++) {
    int g = it * 256 + tid;
    if (g < 704) {
      int d = g >> 3, sc2 = g & 7;
      vreg[it] = *(const short8*)(vtbase + (size_t)d * SPAD + 0 * 64 + sc2 * 8);
    }
  }

  float m_i = -1e30f, l_i = 0.f;
  const f32x4 z4 = {0.f, 0.f, 0.f, 0.f};
  f32x4 o_acc[6];
#pragma unroll
  for (int jd = 0; jd < 6; jd++) o_acc[jd] = z4;

  int cur = 0;
  for (int kt = 0; kt < 17; kt++) {
    // barrier A: previous compute's sVT/sP readers done; drains vmcnt ->
    // K(kt) arrived in sK[cur], vreg holds VT(kt).
    __syncthreads();
#pragma unroll
    for (int it = 0; it < 3; it++) {
      int g = it * 256 + tid;
      if (g < 704) {
        int d = g >> 3, sc2 = g & 7;
        *(short8*)&sVT[d * 72 + sc2 * 8] = vreg[it];
      }
    }
    // barrier B: sVT(kt) visible to all waves (no vmem issued since A -> no drain cost)
    __syncthreads();

    // issue next tile's staging NOW — flies during compute(kt)
    if (kt < 16) {
      int ktn = kt + 1;
#pragma unroll
      for (int ci = 0; ci < 3; ci++) {
        int c = wave + ci * 4;
        if (c < 11) {
          int g = c * 64 + lane;
          int r = g / 11, gc = g - r * 11;
          int t = ktn * 64 + r; if (t > Ssz - 1) t = Ssz - 1;
          const unsigned short* srcp = kbase + (size_t)t * Esz + gc * 8;
          __builtin_amdgcn_global_load_lds(
              (__attribute__((address_space(1))) void*)srcp,
              (__attribute__((address_space(3))) void*)(&sK[cur ^ 1][c * 512]),
              16, 0, 0);
        }
      }
#pragma unroll
      for (int it = 0; it < 3; it++) {
        int g = it * 256 + tid;
        if (g < 704) {
          int d = g >> 3, sc2 = g & 7;
          vreg[it] = *(const short8*)(vtbase + (size_t)d * SPAD + ktn * 64 + sc2 * 8);
        }
      }
    }

    // ---- compute(kt): S^T = K Q^T (col=qrow l15, row=key quad4+r) ----
    const unsigned short* sKc = sK[cur];
    f32x4 stv[4];
#pragma unroll
    for (int j = 0; j < 4; j++) stv[j] = z4;
#pragma unroll
    for (int ks = 0; ks < 3; ks++) {
#pragma unroll
      for (int j = 0; j < 4; j++) {
        short8 bk8 = *(const short8*)&sKc[(j * 16 + l15) * 88 + ks * 32 + quad * 8];
        stv[j] = __builtin_amdgcn_mfma_f32_16x16x32_bf16(bk8, qf[ks], stv[j], 0, 0, 0);
      }
    }

    if (kt == 16) {  // keys 1025..1087 invalid (only key 1024 valid)
#pragma unroll
      for (int j = 0; j < 4; j++)
#pragma unroll
        for (int r = 0; r < 4; r++)
          if (j != 0 || r != 0) stv[j][r] = -1e30f;
      if (quad != 0) stv[0][0] = -1e30f;
    }

    // row max: 15 in-lane + 2 shuffle rounds
    float rmax = stv[0][0];
#pragma unroll
    for (int j = 0; j < 4; j++)
#pragma unroll
      for (int r = 0; r < 4; r++) rmax = fmaxf(rmax, stv[j][r]);
    rmax = fmaxf(rmax, __shfl_xor(rmax, 16, 64));
    rmax = fmaxf(rmax, __shfl_xor(rmax, 32, 64));

    float mnew = fmaxf(m_i, rmax);
    float alpha = fexp2(m_i - mnew);
    m_i = mnew;

    float rsum = 0.f;
#pragma unroll
    for (int j = 0; j < 4; j++) {
      float p0 = fexp2(stv[j][0] - mnew);
      float p1 = fexp2(stv[j][1] - mnew);
      float p2 = fexp2(stv[j][2] - mnew);
      float p3 = fexp2(stv[j][3] - mnew);
      rsum += (p0 + p1) + (p2 + p3);
      unsigned w0 = __builtin_amdgcn_perm(fbits(p1) + 0x8000u, fbits(p0) + 0x8000u, 0x07060302u);
      unsigned w1 = __builtin_amdgcn_perm(fbits(p3) + 0x8000u, fbits(p2) + 0x8000u, 0x07060302u);
      int base = (wave * 16 + l15) * 36 + j * 8 + quad * 2;  // u32 idx (stride 72 ush)
      sPu[base]     = w0;
      sPu[base + 1] = w1;
    }
    rsum += __shfl_xor(rsum, 16, 64);
    rsum += __shfl_xor(rsum, 32, 64);
    l_i = l_i * alpha + rsum;

    float ar[4];
#pragma unroll
    for (int r = 0; r < 4; r++) ar[r] = __shfl(alpha, quad4 + r, 64);
#pragma unroll
    for (int jd = 0; jd < 6; jd++)
#pragma unroll
      for (int r = 0; r < 4; r++) o_acc[jd][r] *= ar[r];

    // PV: same-wave sP round-trip (in-order LDS per wave), no barrier
#pragma unroll
    for (int ks2 = 0; ks2 < 2; ks2++) {
      short8 ap = *(const short8*)&sP[(wave * 16 + l15) * 72 + ks2 * 32 + quad * 8];
#pragma unroll
      for (int jd = 0; jd < 6; jd++) {
        short8 bv8 = *(const short8*)&sVT[(jd * 16 + l15) * 72 + ks2 * 32 + quad * 8];
        o_acc[jd] = __builtin_amdgcn_mfma_f32_16x16x32_bf16(ap, bv8, o_acc[jd], 0, 0, 0);
      }
    }
    cur ^= 1;
  }

  // epilogue: normalize and store
  float lr4[4];
#pragma unroll
  for (int r = 0; r < 4; r++) lr4[r] = __shfl(l_i, quad4 + r, 64);
#pragma unroll
  for (int jd = 0; jd < 6; jd++) {
    int d = jd * 16 + l15;
#pragma unroll
    for (int r = 0; r < 4; r++) {
      int s = qt * 64 + wave * 16 + quad4 + r;
      if (s < Ssz && d < Dsz) {
        float val = o_acc[jd][r] / lr4[r];
        op[((size_t)(bb * Ssz + s)) * Esz + hh * Dsz + d] = f2bf(val);
      }
    }
  }
}

// ---------------- launch ----------------
extern "C" void kernel_launch(void* const* d_in, const int* in_sizes, int n_in,
                              void* d_out, int out_size, void* d_ws, size_t ws_size,
                              hipStream_t stream) {
  const float* hs = (const float*)d_in[0];
  const float* fc = (const float*)d_in[1];
  const float* fs = (const float*)d_in[2];
  const float* Wq = (const float*)d_in[3];
  const float* bq = (const float*)d_in[4];
  const float* Wk = (const float*)d_in[5];
  const float* bk = (const float*)d_in[6];
  const float* Wv = (const float*)d_in[7];
  const float* bv = (const float*)d_in[8];
  const float* Wo = (const float*)d_in[9];
  const float* bo = (const float*)d_in[10];
  float* out = (float*)d_out;

  const size_t ME = (size_t)Msz * Esz;   // 11,545,600
  const size_t EE = (size_t)Esz * Esz;   // 1,982,464
  // Layout: hsb | wqb wkb wvb wob (4EE contiguous -> single cast4) | qb kb vb.
  // VT (12,255,232 ush) overlays hsb..wvb (ME+3EE = 17,492,992) — wob at
  // ME+3EE is beyond VT's end, stays live for the final GEMM.
  unsigned short* hsb = (unsigned short*)d_ws;
  unsigned short* wqb = hsb + ME;
  unsigned short* wkb = wqb + EE;
  unsigned short* wvb = wkb + EE;
  unsigned short* wob = wvb + EE;
  unsigned short* qb  = wob + EE;
  unsigned short* kb  = qb  + ME;
  unsigned short* vb  = kb  + ME;
  unsigned short* vtb = hsb;   // VT overlay
  unsigned short* aob = vb;    // attention output overlays vb (dead after vtrans)

  int nh4 = (int)(ME / 4);
  int nw4 = (int)(EE / 4);
  cast_kernel<<<(nh4 + 255) / 256, 256, 0, stream>>>(hs, hsb, nh4);
  cast4_kernel<<<(4 * nw4 + 255) / 256, 256, 0, stream>>>(Wq, Wk, Wv, Wo, wqb, nw4);

  // fused QKV projection + bias + RoPE + q prescale: N = 3*1408 = 4224
  dim3 gq(33, (Msz + 127) / 128);  // (33, 65)
  gemm_qkv<<<gq, 256, 0, stream>>>(hsb, wqb, bq, bk, bv, fc, fs, qb, Msz, Esz);

  vtrans_kernel<<<dim3(17, Hsz, Bsz), 256, 0, stream>>>(vb, vtb);

  attn_kernel<<<dim3(17, Hsz, Bsz), 256, 0, stream>>>(qb, kb, vtb, aob);

  dim3 gg(Esz / 128, (Msz + 127) / 128);  // (11, 65)
  gemm_bt<0><<<gg, 256, 0, stream>>>(aob, wob, bo, out, Msz, Esz, Esz);
}